// Round 10
// baseline (52.985 us; speedup 1.0000x reference)
//
#include <hip/hip_runtime.h>
#include <math.h>

#define BATCH_C 16384
#define SPW 2   // batch rows per wave (each wave: both sides pooled + head)

typedef float f32x4  __attribute__((ext_vector_type(4)));
typedef f32x4 __attribute__((aligned(4))) f32x4_u;   // dword-aligned vector load
typedef float f32x16 __attribute__((ext_vector_type(16)));
typedef short s16x8  __attribute__((ext_vector_type(8)));

typedef union { unsigned u[4]; s16x8 v; } abfrag_t;

// branchless RNE fp32->bf16 (no NaNs here), result in LOW 16 bits
static __device__ inline unsigned rlo_f(float x) {
    unsigned u = __float_as_uint(x);
    return (u + 0x7fffu + ((u >> 16) & 1u)) >> 16;
}
// same, result pre-positioned in HIGH 16 bits
static __device__ inline unsigned rhi_f(float x) {
    unsigned u = __float_as_uint(x);
    return (u + 0x7fffu + ((u >> 16) & 1u)) & 0xffff0000u;
}

// ---------------------------------------------------------------------------
// Prep: y in {0,1}: segment starts for each side; y==2 (block 0): transpose
// Wc1[128][32] -> Wc1T[32][128] in workspace (head reads it from L2).
// ---------------------------------------------------------------------------
__global__ __launch_bounds__(256) void prep_kernel(
    const int* __restrict__ lseg, const int* __restrict__ rseg, int n,
    const float* __restrict__ Wc1,
    int* __restrict__ lstart, int* __restrict__ rstart,
    float* __restrict__ Wc1T)
{
    if (blockIdx.y == 2) {
        if (blockIdx.x == 0) {
            for (int idx = threadIdx.x; idx < 128 * 32; idx += 256)
                Wc1T[(idx & 31) * 128 + (idx >> 5)] = Wc1[idx];
        }
        return;
    }
    const int* __restrict__ seg = blockIdx.y ? rseg : lseg;
    int* __restrict__ start = blockIdx.y ? rstart : lstart;
    int i = blockIdx.x * blockDim.x + threadIdx.x;
    if (i >= n) return;
    int s = seg[i];
    int prev = (i == 0) ? -1 : seg[i - 1];
    for (int b = prev + 1; b <= s; ++b) start[b] = i;
    if (i == n - 1) {
        for (int b = s + 1; b <= BATCH_C; ++b) start[b] = n;
    }
}

// ---------------------------------------------------------------------------
// Fused pool+head. Mixed-side MFMA windows: rows 0-15 = left units, rows
// 16-31 = right units (C regs 0-7 / 8-15 split by construction). 3-stage
// software pipeline: FETCH(w+2) || CONV(w+1) || MFMA+EPI(w), with separate
// fetch-side and epilogue-side segment cursors (identical step sequences).
// Masking fully resolved at FETCH (invalid rows zeroed; ones-bit for the
// bias column carried per-window). bf16 3-term split as R7-R9.
// ---------------------------------------------------------------------------
__global__ __launch_bounds__(256, 3) void fused_kernel(
    const float* __restrict__ lfeats, const float* __restrict__ rfeats,
    const int* __restrict__ lstart, const int* __restrict__ rstart,
    const float* __restrict__ W1, const float* __restrict__ b1,
    const float* __restrict__ Wc1T, const float* __restrict__ bc1,
    const float* __restrict__ Wc2, const float* __restrict__ bc2,
    float* __restrict__ out, int nunits)
{
    const int lane = threadIdx.x & 63;
    const int wv   = threadIdx.x >> 6;
    const int S0   = (blockIdx.x * 4 + wv) * SPW;
    const int r    = lane & 31;    // A row / B col within tile
    const int hh   = lane >> 5;    // k-half
    const int nmax = nunits - 1;
    const int ofs1 = hh ? 5 : 4;
    const bool left = r < 16;
    const int rr = left ? r : r - 16;

    __shared__ __align__(16) short sBh[2][32][16];
    __shared__ __align__(16) short sBl[2][32][16];
    __shared__ __align__(16) float rowbuf[4][SPW][128];

    // ---- B fragments (W1 cols + bias row at k=9, hi/lo), once per block ----
    {
        const int t = threadIdx.x;
        const int tile = t >> 7, col = (t >> 2) & 31, k0 = (t & 3) * 4;
        const int ch = tile * 32 + col;
#pragma unroll
        for (int q = 0; q < 4; ++q) {
            const int k = k0 + q;
            float v = 0.0f;
            if (k < 9) v = W1[k * 64 + ch];
            else if (k == 9) v = b1[ch];
            unsigned hi = rlo_f(v);
            float d = v - __uint_as_float(hi << 16);
            sBh[tile][col][k] = (short)hi;
            sBl[tile][col][k] = (short)rlo_f(d);
        }
    }
    __syncthreads();
    const s16x8 bh0 = *(const s16x8*)&sBh[0][r][hh * 8];
    const s16x8 bh1 = *(const s16x8*)&sBh[1][r][hh * 8];
    const s16x8 bl0 = *(const s16x8*)&sBl[0][r][hh * 8];
    const s16x8 bl1 = *(const s16x8*)&sBl[1][r][hh * 8];
    const f32x16 kZ = (f32x16)0.0f;

    // ---- segment boundaries -> SGPR ----
    const int bidx = S0 + (lane <= SPW ? lane : SPW);
    int svl = lstart[bidx], svr = rstart[bidx];
    const int sL  = __builtin_amdgcn_readfirstlane(__shfl(svl, 0, 64));
    const int e1L = __builtin_amdgcn_readfirstlane(__shfl(svl, 1, 64));
    const int e2L = __builtin_amdgcn_readfirstlane(__shfl(svl, 2, 64));
    const int sR  = __builtin_amdgcn_readfirstlane(__shfl(svr, 0, 64));
    const int e1R = __builtin_amdgcn_readfirstlane(__shfl(svr, 1, 64));
    const int e2R = __builtin_amdgcn_readfirstlane(__shfl(svr, 2, 64));

    // fetch-side and epilogue-side cursors (identical step sequences)
    int bLF = sL, ecLF = e1L, csLF = 0;
    int bRF = sR, ecRF = e1R, csRF = 0;
    int bLE = sL, ecLE = e1L, csLE = 0;
    int bRE = sR, ecRE = e1R, csRE = 0;
    float accL0 = 0.f, accL1 = 0.f, accR0 = 0.f, accR1 = 0.f;

#define FETCHW(Q0,Q1,Q2,Q3,Q4,Q5,Q6,Q7,ONES) do {                          \
    while (bLF >= ecLF && csLF < SPW) { ++csLF; ecLF = e2L; }               \
    while (bRF >= ecRF && csRF < SPW) { ++csRF; ecRF = e2R; }               \
    int sl_ = ecLF - bLF; sl_ = sl_ < 0 ? 0 : (sl_ > 16 ? 16 : sl_);        \
    int sr_ = ecRF - bRF; sr_ = sr_ < 0 ? 0 : (sr_ > 16 ? 16 : sr_);        \
    int idx_ = left ? (bLF + rr) : (bRF + rr);                              \
    int u_ = idx_ > nmax ? nmax : idx_;                                     \
    const float* fp_ = (left ? lfeats : rfeats) + (size_t)u_ * 9;           \
    f32x4 x0_ = *(const f32x4_u*)fp_;                                       \
    f32x4 x1_ = *(const f32x4_u*)(fp_ + ofs1);                              \
    const bool val_  = rr < (left ? sl_ : sr_);                             \
    const bool keep_ = val_ && (hh == 0);                                   \
    Q0 = val_  ? (hh ? x1_.w : x0_.x) : 0.f;                                \
    Q1 = keep_ ? x0_.y : 0.f;                                               \
    Q2 = keep_ ? x0_.z : 0.f;                                               \
    Q3 = keep_ ? x0_.w : 0.f;                                               \
    Q4 = keep_ ? x1_.x : 0.f;                                               \
    Q5 = keep_ ? x1_.y : 0.f;                                               \
    Q6 = keep_ ? x1_.z : 0.f;                                               \
    Q7 = keep_ ? x1_.w : 0.f;                                               \
    ONES = (val_ && hh) ? 0x3F800000u : 0u;                                 \
    bLF += sl_; bRF += sr_;                                                 \
} while (0)

#define CONVW(Q0,Q1,Q2,Q3,Q4,Q5,Q6,Q7,ONES,AH,AL) do {                     \
    unsigned u0_=__float_as_uint(Q0), u1_=__float_as_uint(Q1),              \
             u2_=__float_as_uint(Q2), u3_=__float_as_uint(Q3),              \
             u4_=__float_as_uint(Q4), u5_=__float_as_uint(Q5),              \
             u6_=__float_as_uint(Q6), u7_=__float_as_uint(Q7);              \
    float d0_=Q0-__uint_as_float(u0_&0xffff0000u);                          \
    float d1_=Q1-__uint_as_float(u1_&0xffff0000u);                          \
    float d2_=Q2-__uint_as_float(u2_&0xffff0000u);                          \
    float d3_=Q3-__uint_as_float(u3_&0xffff0000u);                          \
    float d4_=Q4-__uint_as_float(u4_&0xffff0000u);                          \
    float d5_=Q5-__uint_as_float(u5_&0xffff0000u);                          \
    float d6_=Q6-__uint_as_float(u6_&0xffff0000u);                          \
    float d7_=Q7-__uint_as_float(u7_&0xffff0000u);                          \
    AH.u[0] = (u0_>>16) | (u1_&0xffff0000u) | ONES;                         \
    AH.u[1] = (u2_>>16) | (u3_&0xffff0000u);                                \
    AH.u[2] = (u4_>>16) | (u5_&0xffff0000u);                                \
    AH.u[3] = (u6_>>16) | (u7_&0xffff0000u);                                \
    AL.u[0] = rlo_f(d0_) | rhi_f(d1_);                                      \
    AL.u[1] = rlo_f(d2_) | rhi_f(d3_);                                      \
    AL.u[2] = rlo_f(d4_) | rhi_f(d5_);                                      \
    AL.u[3] = rlo_f(d6_) | rhi_f(d7_);                                      \
} while (0)

#define MFMAC(AH,AL,C0,C1) do {                                             \
    C0 = __builtin_amdgcn_mfma_f32_32x32x16_bf16(AL.v, bh0, kZ, 0,0,0);     \
    C0 = __builtin_amdgcn_mfma_f32_32x32x16_bf16(AH.v, bl0, C0, 0,0,0);     \
    C0 = __builtin_amdgcn_mfma_f32_32x32x16_bf16(AH.v, bh0, C0, 0,0,0);     \
    C1 = __builtin_amdgcn_mfma_f32_32x32x16_bf16(AL.v, bh1, kZ, 0,0,0);     \
    C1 = __builtin_amdgcn_mfma_f32_32x32x16_bf16(AH.v, bl1, C1, 0,0,0);     \
    C1 = __builtin_amdgcn_mfma_f32_32x32x16_bf16(AH.v, bh1, C1, 0,0,0);     \
} while (0)

#define EPIC(C0,C1) do {                                                    \
    float l0_=0.f,l1_=0.f,r0_=0.f,r1_=0.f;                                  \
    _Pragma("unroll")                                                       \
    for (int t_=0; t_<8; ++t_) {                                            \
        l0_ += fmaxf(C0[t_],0.f);  l1_ += fmaxf(C1[t_],0.f);                \
        r0_ += fmaxf(C0[t_+8],0.f); r1_ += fmaxf(C1[t_+8],0.f);             \
    }                                                                       \
    accL0 += l0_; accL1 += l1_; accR0 += r0_; accR1 += r1_;                 \
} while (0)

#define FLUSHW(S, OFS) do {                                                 \
    while (cs##S##E < SPW && b##S##E >= ec##S##E) {                         \
        float m0_ = acc##S##0 + __shfl_xor(acc##S##0, 32, 64);              \
        float m1_ = acc##S##1 + __shfl_xor(acc##S##1, 32, 64);              \
        rowbuf[wv][cs##S##E][(OFS) + lane] = hh ? m1_ : m0_;                \
        acc##S##0 = 0.f; acc##S##1 = 0.f;                                   \
        ++cs##S##E; ec##S##E = e2##S;                                       \
    }                                                                       \
} while (0)

#define ESTEP() do {                                                        \
    int tl_ = ecLE - bLE; tl_ = tl_ < 0 ? 0 : (tl_ > 16 ? 16 : tl_);        \
    int tr_ = ecRE - bRE; tr_ = tr_ < 0 ? 0 : (tr_ > 16 ? 16 : tr_);        \
    bLE += tl_; bRE += tr_;                                                 \
    FLUSHW(L, 0); FLUSHW(R, 64);                                            \
} while (0)

    float rA0,rA1,rA2,rA3,rA4,rA5,rA6,rA7; unsigned oA;
    float rB0,rB1,rB2,rB3,rB4,rB5,rB6,rB7; unsigned oB;
    abfrag_t aAH, aAL, aBH, aBL;

    // prime: fetch w0, w1; convert w0
    FETCHW(rA0,rA1,rA2,rA3,rA4,rA5,rA6,rA7,oA);
    FETCHW(rB0,rB1,rB2,rB3,rB4,rB5,rB6,rB7,oB);
    CONVW(rA0,rA1,rA2,rA3,rA4,rA5,rA6,rA7,oA, aAH, aAL);

    // leading empty segments
    FLUSHW(L, 0); FLUSHW(R, 64);

    while ((csLE < SPW) || (csRE < SPW)) {
        {   // phase A: EPI window from aA*, next raw is rB*
            f32x16 c0, c1;
            MFMAC(aAH, aAL, c0, c1);
            FETCHW(rA0,rA1,rA2,rA3,rA4,rA5,rA6,rA7,oA);
            CONVW(rB0,rB1,rB2,rB3,rB4,rB5,rB6,rB7,oB, aBH, aBL);
            EPIC(c0, c1);
            ESTEP();
        }
        if (!((csLE < SPW) || (csRE < SPW))) break;
        {   // phase B: mirror
            f32x16 c0, c1;
            MFMAC(aBH, aBL, c0, c1);
            FETCHW(rB0,rB1,rB2,rB3,rB4,rB5,rB6,rB7,oB);
            CONVW(rA0,rA1,rA2,rA3,rA4,rA5,rA6,rA7,oA, aAH, aAL);
            EPIC(c0, c1);
            ESTEP();
        }
    }

#undef ESTEP
#undef FLUSHW
#undef EPIC
#undef MFMAC
#undef CONVW
#undef FETCHW

    // drain rowbuf ds_writes (same-wave RAW)
    asm volatile("s_waitcnt lgkmcnt(0)" ::: "memory");

    // ================= HEAD: 2 rows per wave (half-wave each) ==============
    {
        const int j = lane & 31;
        const float* __restrict__ rb = &rowbuf[wv][hh][0];
        const float* __restrict__ wt = Wc1T + j * 128;

        float accA = bc1[j], accB = 0.0f;
#pragma unroll 8
        for (int q = 0; q < 32; ++q) {
            f32x4 v = *(const f32x4*)(rb + q * 4);
            f32x4 w = *(const f32x4*)(wt + q * 4);
            accA = fmaf(v.x, w.x, accA);
            accB = fmaf(v.y, w.y, accB);
            accA = fmaf(v.z, w.z, accA);
            accB = fmaf(v.w, w.w, accB);
        }
        float hsv = fmaxf(accA + accB, 0.0f) * Wc2[j];
#pragma unroll
        for (int off = 16; off > 0; off >>= 1) hsv += __shfl_xor(hsv, off, 64);

        if (j == 0) {
            float logit = hsv + bc2[0];
            out[S0 + hh] = 1.0f / (1.0f + expf(-logit));
        }
    }
}

// ---------------------------------------------------------------------------
extern "C" void kernel_launch(void* const* d_in, const int* in_sizes, int n_in,
                              void* d_out, int out_size, void* d_ws, size_t ws_size,
                              hipStream_t stream)
{
    const float* lfeats = (const float*)d_in[0];
    const float* rfeats = (const float*)d_in[1];
    const int*   lseg   = (const int*)d_in[2];
    const int*   rseg   = (const int*)d_in[3];
    const float* W1     = (const float*)d_in[4];
    const float* b1     = (const float*)d_in[5];
    const float* Wc1    = (const float*)d_in[6];
    const float* bc1    = (const float*)d_in[7];
    const float* Wc2    = (const float*)d_in[8];
    const float* bc2    = (const float*)d_in[9];
    float* out = (float*)d_out;

    const int n = in_sizes[2];  // N_UNITS per side

    int* lstart = (int*)d_ws;
    int* rstart = lstart + (BATCH_C + 16);
    float* Wc1T = (float*)(rstart + (BATCH_C + 16));   // 131200 B offset, 16B-aligned

    prep_kernel<<<dim3((n + 255) / 256, 3), 256, 0, stream>>>(
        lseg, rseg, n, Wc1, lstart, rstart, Wc1T);

    fused_kernel<<<BATCH_C / (SPW * 4), 256, 0, stream>>>(
        lfeats, rfeats, lstart, rstart, W1, b1, Wc1T, bc1, Wc2, bc2, out, n);
}